// Round 7
// baseline (82.506 us; speedup 1.0000x reference)
//
#include <hip/hip_runtime.h>
#include <math.h>

#define NB 2048
#define NS 200
#define ND 128

typedef __attribute__((ext_vector_type(8))) short bf16x8;
typedef __attribute__((ext_vector_type(4))) float f32x4;
typedef __attribute__((ext_vector_type(4))) unsigned short u16x4;

// LDS layout (u32 units)
#define U_W1HI  0                  // 64 x 136 u16 = 4352 u32
#define U_W1LO  4352               // 4352 u32
#define U_Q     8704               // 128 f32
#define U_BIAS  8832               // 64 f32
#define U_B2    8896               // 32 f32
#define U_W3    8928               // 32 f32
#define U_SC    8960               // 208 f32 (masked+decayed scores)
#define U_DM    9168               // 208 f32 (decay*mask factors)
#define U_O4    9376               // 4*128 f32 per-wave weighted-sum partials
#define U_ML    9888               // 8 f32 (m,l per wave)
#define U_BP    9896               // 260 f32 (phase0 bias partials)
#define U_TOTAL 10156              // 40624 B -> 3 blocks/CU at bounds(256,3)

extern "C" __global__ void __launch_bounds__(256, 3)
tdra_main(const float* __restrict__ query,
          const float* __restrict__ keys,
          const int*   __restrict__ kmask,
          const float* __restrict__ W1,
          const float* __restrict__ b1,
          const float* __restrict__ a1p,
          const float* __restrict__ W2,
          const float* __restrict__ b2,
          const float* __restrict__ a2p,
          const float* __restrict__ W3,
          const float* __restrict__ b3p,
          float* __restrict__ out)
{
    __shared__ __align__(16) unsigned int smem[U_TOTAL];
    unsigned short* W1hi = (unsigned short*)(smem + U_W1HI);
    unsigned short* W1lo = (unsigned short*)(smem + U_W1LO);
    float* qf    = (float*)(smem + U_Q);
    float* biasE = (float*)(smem + U_BIAS);
    float* b2f   = (float*)(smem + U_B2);
    float* w3f   = (float*)(smem + U_W3);
    float* scf   = (float*)(smem + U_SC);
    float* dmf   = (float*)(smem + U_DM);
    float* o4    = (float*)(smem + U_O4);
    float* mlf   = (float*)(smem + U_ML);
    float* bpf   = (float*)(smem + U_BP);

    const int tid = threadIdx.x;
    const int b   = blockIdx.x;
    const float a1 = a1p[0];
    const float a2 = a2p[0];
    const float b3 = b3p[0];

    const int wv = tid >> 6;
    const int c  = tid & 15;
    const int G  = (tid >> 4) & 3;

    // ---------- Phase 0a: q, b2, W3, decay/mask table ----------
    if (tid < 32) {
        float4 qv = *(const float4*)(query + (size_t)b * ND + tid * 4);
        *(float4*)(qf + tid * 4) = qv;
    } else if (tid < 64) {
        b2f[tid - 32] = b2[tid - 32];
    } else if (tid < 96) {
        w3f[tid - 64] = W3[tid - 64];
    }
    if (tid < 208) {
        int mk = (tid < NS) ? kmask[(size_t)b * NS + tid] : 0;
        dmf[tid] = mk ? expf(0.1f * (float)(tid - (NS - 1))) : 0.f;
    }

    // A2 = W2^T fragments straight from global (st-invariant, L2-hit)
    bf16x8 A2h[2][2], A2l[2][2];
    #pragma unroll
    for (int jt = 0; jt < 2; ++jt)
        #pragma unroll
        for (int kt = 0; kt < 2; ++kt)
            #pragma unroll
            for (int e = 0; e < 8; ++e) {
                float x = W2[(kt * 32 + 8 * G + e) * 32 + jt * 16 + c];
                unsigned int u  = __float_as_uint(x);
                unsigned int hb = u & 0xFFFF0000u;
                float lof = x - __uint_as_float(hb);
                A2h[jt][kt][e] = (short)(u >> 16);
                A2l[jt][kt][e] = (short)(__float_as_uint(lof) >> 16);
            }
    __syncthreads();

    // ---------- Phase 0b: W1 planes = split(W1a+W1d+q*W1c); bias partials ----
    {
        int h = tid & 63, dg = tid >> 6;
        #pragma unroll 2
        for (int i = 0; i < 8; ++i) {
            int dblk = dg * 8 + i;
            u16x4 hi4, lo4;
            #pragma unroll
            for (int jj = 0; jj < 4; ++jj) {
                int d = dblk * 4 + jj;
                float qd = qf[d];
                float va = W1[d * 64 + h];
                float vc = W1[16384 + d * 64 + h];
                float vd = W1[24576 + d * 64 + h];
                float x  = va + vd + qd * vc;
                unsigned int u  = __float_as_uint(x);
                unsigned int hb = u & 0xFFFF0000u;
                float lof = x - __uint_as_float(hb);
                hi4[jj] = (unsigned short)(u >> 16);
                lo4[jj] = (unsigned short)(__float_as_uint(lof) >> 16);
            }
            *(u16x4*)(W1hi + h * 136 + dblk * 4) = hi4;
            *(u16x4*)(W1lo + h * 136 + dblk * 4) = lo4;
        }
        int qt = dg;
        const float* pb = W1 + (size_t)(128 + qt * 32) * 64 + h;
        const float* pd = W1 + (size_t)(384 + qt * 32) * 64 + h;
        float p = 0.f;
        #pragma unroll 8
        for (int i = 0; i < 32; ++i)
            p = fmaf(qf[qt * 32 + i], pb[i * 64] - pd[i * 64], p);
        bpf[qt * 65 + h] = p;
    }
    __syncthreads();
    if (tid < 64)
        biasE[tid] = b1[tid] + bpf[tid] + bpf[65 + tid] + bpf[130 + tid] + bpf[195 + tid];
    __syncthreads();

    // ---------- Main: online-softmax state per lane ----------
    float m_run = -INFINITY, l_run = 0.f;
    float o_acc[32];
    #pragma unroll
    for (int i = 0; i < 32; ++i) o_acc[i] = 0.f;

    #pragma unroll 1
    for (int st = wv; st < 13; st += 4) {
        const int rr = st * 16 + c;              // semantic row (may be >=200)
        int row_ld = rr < 199 ? rr : 199;        // clamped load row
        const float* kp = keys + ((size_t)b * NS + row_ld) * ND + 8 * G;

        // keys f32 -> B1 hi/lo frags (staggered)
        bf16x8 B1h[4], B1l[4];
        #pragma unroll
        for (int half = 0; half < 2; ++half) {
            float4 xs[4];
            #pragma unroll
            for (int q_ = 0; q_ < 2; ++q_) {
                xs[2 * q_]     = *(const float4*)(kp + (2 * half + q_) * 32);
                xs[2 * q_ + 1] = *(const float4*)(kp + (2 * half + q_) * 32 + 4);
            }
            #pragma unroll
            for (int q_ = 0; q_ < 2; ++q_) {
                int dt = 2 * half + q_;
                float t_[8] = {xs[2*q_].x, xs[2*q_].y, xs[2*q_].z, xs[2*q_].w,
                               xs[2*q_+1].x, xs[2*q_+1].y, xs[2*q_+1].z, xs[2*q_+1].w};
                #pragma unroll
                for (int e = 0; e < 8; ++e) {
                    unsigned int u  = __float_as_uint(t_[e]);
                    unsigned int hb = u & 0xFFFF0000u;
                    float lof = t_[e] - __uint_as_float(hb);
                    B1h[dt][e] = (short)(u >> 16);
                    B1l[dt][e] = (short)(__float_as_uint(lof) >> 16);
                }
            }
        }

        // GEMM1': acc1[ht] = bias + W1eff^T x K^T
        f32x4 acc1[4];
        #pragma unroll
        for (int ht = 0; ht < 4; ++ht)
            acc1[ht] = *(const f32x4*)(biasE + 16 * ht + 4 * G);
        #pragma unroll
        for (int dt = 0; dt < 4; ++dt) {
            #pragma unroll
            for (int ht = 0; ht < 4; ++ht) {
                int idx = (16 * ht + c) * 136 + 32 * dt + 8 * G;
                bf16x8 A1h = *(const bf16x8*)(W1hi + idx);
                bf16x8 A1l = *(const bf16x8*)(W1lo + idx);
                acc1[ht] = __builtin_amdgcn_mfma_f32_16x16x32_bf16(A1h, B1h[dt], acc1[ht], 0, 0, 0);
                acc1[ht] = __builtin_amdgcn_mfma_f32_16x16x32_bf16(A1h, B1l[dt], acc1[ht], 0, 0, 0);
                acc1[ht] = __builtin_amdgcn_mfma_f32_16x16x32_bf16(A1l, B1h[dt], acc1[ht], 0, 0, 0);
            }
        }

        // PReLU -> packed hi|lo h1
        unsigned int p[4][4];
        #pragma unroll
        for (int ht = 0; ht < 4; ++ht)
            #pragma unroll
            for (int r = 0; r < 4; ++r) {
                float v = acc1[ht][r];
                v = fmaxf(v, 0.f) + a1 * fminf(v, 0.f);
                unsigned int u  = __float_as_uint(v);
                unsigned int hb = u & 0xFFFF0000u;
                float lof = v - __uint_as_float(hb);
                p[ht][r] = (u >> 16) | (__float_as_uint(lof) & 0xFFFF0000u);
            }

        // GEMM2': shfl-transpose h1 into B2 frags
        f32x4 acc2[2];
        acc2[0] = *(const f32x4*)(b2f + 4 * G);
        acc2[1] = *(const f32x4*)(b2f + 16 + 4 * G);
        const int srcbase = ((tid & 16) ? 32 : 0) + c;
        #pragma unroll
        for (int kt = 0; kt < 2; ++kt) {
            unsigned int q[8];
            #pragma unroll
            for (int half = 0; half < 2; ++half) {
                int src = srcbase + half * 16;
                #pragma unroll
                for (int r = 0; r < 4; ++r) {
                    unsigned int v0 = (unsigned int)__shfl((int)p[2 * kt][r], src, 64);
                    unsigned int v1 = (unsigned int)__shfl((int)p[2 * kt + 1][r], src, 64);
                    q[half * 4 + r] = (tid & 32) ? v1 : v0;
                }
            }
            bf16x8 B2h_, B2l_;
            #pragma unroll
            for (int e = 0; e < 8; ++e) {
                B2h_[e] = (short)(q[e] & 0xFFFFu);
                B2l_[e] = (short)(q[e] >> 16);
            }
            #pragma unroll
            for (int jt = 0; jt < 2; ++jt) {
                acc2[jt] = __builtin_amdgcn_mfma_f32_16x16x32_bf16(A2h[jt][kt], B2h_, acc2[jt], 0, 0, 0);
                acc2[jt] = __builtin_amdgcn_mfma_f32_16x16x32_bf16(A2h[jt][kt], B2l_, acc2[jt], 0, 0, 0);
                acc2[jt] = __builtin_amdgcn_mfma_f32_16x16x32_bf16(A2l[jt][kt], B2h_, acc2[jt], 0, 0, 0);
            }
        }

        // score: PReLU + W3-dot in-lane, xor-reduce over G -> all lanes have it
        float sv = 0.f;
        #pragma unroll
        for (int jt = 0; jt < 2; ++jt)
            #pragma unroll
            for (int r = 0; r < 4; ++r) {
                float v = acc2[jt][r];
                v = fmaxf(v, 0.f) + a2 * fminf(v, 0.f);
                sv = fmaf(v, w3f[jt * 16 + 4 * G + r], sv);
            }
        sv += __shfl_xor(sv, 16, 64);
        sv += __shfl_xor(sv, 32, 64);

        // decay + mask (dmf[rr]=0 for masked or rr>=200)
        float dm  = dmf[rr];
        float scm = (dm > 0.f) ? (sv + b3) * dm : -INFINITY;
        if ((tid & 48) == 0 && rr < NS) scf[rr] = scm;

        // online softmax update
        if (scm > m_run) {
            float f = __expf(m_run - scm);     // m_run=-inf -> 0, no NaN
            l_run *= f;
            #pragma unroll
            for (int i = 0; i < 32; ++i) o_acc[i] *= f;
            m_run = scm;
        }
        float wexp = (scm == -INFINITY) ? 0.f : __expf(scm - m_run);
        l_run += wexp;
        #pragma unroll
        for (int dt = 0; dt < 4; ++dt)
            #pragma unroll
            for (int e = 0; e < 8; ++e) {
                float kv = __uint_as_float(((unsigned int)(unsigned short)B1h[dt][e]) << 16)
                         + __uint_as_float(((unsigned int)(unsigned short)B1l[dt][e]) << 16);
                o_acc[dt * 8 + e] = fmaf(wexp, kv, o_acc[dt * 8 + e]);
            }
    }

    // ---------- in-wave combine over the 16 c-lanes (rescaled merge) ----------
    #pragma unroll
    for (int d_ = 1; d_ < 16; d_ <<= 1) {
        float mo = __shfl_xor(m_run, d_, 64);
        float lo = __shfl_xor(l_run, d_, 64);
        float M2 = fmaxf(m_run, mo);
        float fs = (m_run == -INFINITY) ? 0.f : __expf(m_run - M2);
        float fo = (mo    == -INFINITY) ? 0.f : __expf(mo    - M2);
        l_run = l_run * fs + lo * fo;
        #pragma unroll
        for (int i = 0; i < 32; ++i) {
            float oo = __shfl_xor(o_acc[i], d_, 64);
            o_acc[i] = o_acc[i] * fs + oo * fo;
        }
        m_run = M2;
    }
    // lanes c==0: write per-wave partials
    if ((tid & 15) == 0) {
        #pragma unroll
        for (int dt = 0; dt < 4; ++dt) {
            *(float4*)(o4 + wv * 128 + 32 * dt + 8 * G) =
                make_float4(o_acc[8*dt+0], o_acc[8*dt+1], o_acc[8*dt+2], o_acc[8*dt+3]);
            *(float4*)(o4 + wv * 128 + 32 * dt + 8 * G + 4) =
                make_float4(o_acc[8*dt+4], o_acc[8*dt+5], o_acc[8*dt+6], o_acc[8*dt+7]);
        }
    }
    if ((tid & 63) == 0) { mlf[2 * wv] = m_run; mlf[2 * wv + 1] = l_run; }
    __syncthreads();

    // ---------- final combine + outputs ----------
    float M = fmaxf(fmaxf(mlf[0], mlf[2]), fmaxf(mlf[4], mlf[6]));
    float fw0 = (mlf[0] == -INFINITY) ? 0.f : __expf(mlf[0] - M);
    float fw1 = (mlf[2] == -INFINITY) ? 0.f : __expf(mlf[2] - M);
    float fw2 = (mlf[4] == -INFINITY) ? 0.f : __expf(mlf[4] - M);
    float fw3 = (mlf[6] == -INFINITY) ? 0.f : __expf(mlf[6] - M);
    float L = mlf[1] * fw0 + mlf[3] * fw1 + mlf[5] * fw2 + mlf[7] * fw3;

    if (tid < ND) {
        float od = o4[tid] * fw0 + o4[128 + tid] * fw1
                 + o4[256 + tid] * fw2 + o4[384 + tid] * fw3;
        out[(size_t)b * ND + tid] = (L > 0.f) ? od / L : 0.f;
    }
    if (tid < NS) {
        float s_ = scf[tid];
        float wv_ = (L > 0.f && s_ > -INFINITY) ? __expf(s_ - M) / L : 0.f;
        out[(size_t)NB * ND + (size_t)b * NS + tid] = wv_;
    }
}

extern "C" void kernel_launch(void* const* d_in, const int* in_sizes, int n_in,
                              void* d_out, int out_size, void* d_ws, size_t ws_size,
                              hipStream_t stream) {
    (void)in_sizes; (void)n_in; (void)d_ws; (void)ws_size; (void)out_size;
    const float* query = (const float*)d_in[0];
    const float* keys  = (const float*)d_in[1];
    const int*   kmask = (const int*)d_in[2];
    const float* W1 = (const float*)d_in[3];
    const float* b1 = (const float*)d_in[4];
    const float* a1 = (const float*)d_in[5];
    const float* W2 = (const float*)d_in[6];
    const float* b2 = (const float*)d_in[7];
    const float* a2 = (const float*)d_in[8];
    const float* W3 = (const float*)d_in[9];
    const float* b3 = (const float*)d_in[10];
    float* out = (float*)d_out;

    hipLaunchKernelGGL(tdra_main, dim3(NB), dim3(256), 0, stream,
                       query, keys, kmask, W1, b1, a1, W2, b2, a2, W3, b3, out);
}